// Round 13
// baseline (1034.245 us; speedup 1.0000x reference)
//
#include <hip/hip_runtime.h>
#include <hip/hip_bf16.h>
#include <stdint.h>

#define NU 100000
#define NI 50000
#define NB 1000
#define NN 151000      // total nodes
#define D  64
#define NE 10000000

#define BSH   6                   // 64 rows per bucket
#define BROWS 64
#define NBUCK 2360                // ceil(NN / 64)
#define CAPB  5632                // k_csr LDS capacity (bucket mean 4238, +21 sigma)
#define BINB  512                 // k_bin blocks (2 per CU)
#define BINT  1024                // k_bin threads per block
#define PSTR  2368                // prefarr row stride (>= NBUCK+1)

typedef unsigned short u16;
typedef unsigned int   u32;

__device__ __forceinline__ u16 f2bf(float f) {
    union { float f; u32 i; } c; c.f = f;
    u32 lsb = (c.i >> 16) & 1;          // round-to-nearest-even bf16
    c.i += 0x7fffu + lsb;
    return (u16)(c.i >> 16);
}

// ---- phase 1: block-local counting sort into the block's OWN contiguous
// window [e0,e1). Stores are random only within 156KB -> L2-resident lines,
// write amp ~1x. No global atomics; per-block bucket prefixes go to prefarr.
__global__ __launch_bounds__(BINT) void k_bin(
    const int* __restrict__ rows, const int* __restrict__ cols,
    const float* __restrict__ vals,
    int* __restrict__ prefarr, int2* __restrict__ subbuf) {
    __shared__ int hcnt[NBUCK];   // 9.4 KB
    __shared__ int hcur[NBUCK];   // 9.4 KB
    __shared__ int tsum[BINT];    // 4 KB
    int b = blockIdx.x, tid = threadIdx.x;
    long e0 = (long)b * NE / BINB;
    long e1 = (long)(b + 1) * NE / BINB;
    for (int j = tid; j < NBUCK; j += BINT) hcnt[j] = 0;
    __syncthreads();
    for (long i = e0 + tid; i < e1; i += BINT)
        atomicAdd(&hcnt[rows[i] >> BSH], 1);            // LDS atomic
    __syncthreads();
    // block-level exclusive scan over the 2360 bucket counts (3 per thread)
    int base3 = tid * 3;
    int v0 = (base3     < NBUCK) ? hcnt[base3]     : 0;
    int v1 = (base3 + 1 < NBUCK) ? hcnt[base3 + 1] : 0;
    int v2 = (base3 + 2 < NBUCK) ? hcnt[base3 + 2] : 0;
    int lsum = v0 + v1 + v2;
    tsum[tid] = lsum;
    __syncthreads();
    for (int d = 1; d < BINT; d <<= 1) {               // Hillis-Steele inclusive
        int t = (tid >= d) ? tsum[tid - d] : 0;
        __syncthreads();
        tsum[tid] += t;
        __syncthreads();
    }
    int excl = tsum[tid] - lsum;
    int* prow = prefarr + (size_t)b * PSTR;
    if (base3     < NBUCK) { hcur[base3]     = excl;           prow[base3]     = excl; }
    if (base3 + 1 < NBUCK) { hcur[base3 + 1] = excl + v0;      prow[base3 + 1] = excl + v0; }
    if (base3 + 2 < NBUCK) { hcur[base3 + 2] = excl + v0 + v1; prow[base3 + 2] = excl + v0 + v1; }
    if (tid == BINT - 1) prow[NBUCK] = tsum[tid];      // == e1-e0
    __syncthreads();
    for (long i = e0 + tid; i < e1; i += BINT) {
        int r  = rows[i];
        int bk = r >> BSH;
        int pos = atomicAdd(&hcur[bk], 1);             // LDS atomic rank
        subbuf[e0 + pos] =
            make_int2(((r & (BROWS - 1)) << 18) | cols[i], __float_as_int(vals[i]));
    }
}

// ---- phase 2: per-bucket CSR build; gather 512 small contiguous chunks
// (L3 reads, no RMW), order in LDS, dump sequentially.
__global__ __launch_bounds__(256) void k_csr(
    const int* __restrict__ prefarr, const int2* __restrict__ subbuf,
    int* __restrict__ off, int* __restrict__ cnt, int* __restrict__ gtotal,
    int2* __restrict__ cicv) {
    __shared__ int rcnt[BROWS], rexc[BROWS], lcur[BROWS];
    __shared__ int csta[BINB], clen[BINB];   // 4 KB
    __shared__ int sbase, stot;
    __shared__ int2 sbuf[CAPB];              // 45 KB
    int b = blockIdx.x, tid = threadIdx.x;
    for (int blk = tid; blk < BINB; blk += 256) {
        const int* prow = prefarr + (size_t)blk * PSTR;
        int s = prow[b];
        int e = prow[b + 1];
        csta[blk] = (int)((long)blk * NE / BINB) + s;
        clen[blk] = e - s;
    }
    if (tid < BROWS) rcnt[tid] = 0;
    __syncthreads();
    // pass 1: row histogram from chunk reads
    for (int blk = tid; blk < BINB; blk += 256) {
        const int2* src = subbuf + csta[blk];
        int l = clen[blk];
        for (int k = 0; k < l; ++k)
            atomicAdd(&rcnt[(u32)src[k].x >> 18], 1);
    }
    __syncthreads();
    if (tid < 64) {
        int v = rcnt[tid], x = v;
        for (int d = 1; d < 64; d <<= 1) {
            int t = __shfl_up(x, d);
            if (tid >= d) x += t;
        }
        rexc[tid] = x - v;
        if (tid == 63) {
            stot = x;
            sbase = atomicAdd(gtotal, x);   // disjoint segments, order-free
        }
    }
    __syncthreads();
    int base = sbase;
    if (tid < BROWS) {
        int r = b * BROWS + tid;
        if (r < NN) { off[r] = base + rexc[tid]; cnt[r] = rcnt[tid]; }
        lcur[tid] = rexc[tid];
    }
    __syncthreads();
    // pass 2: re-read chunks, scatter into LDS in CSR order
    for (int blk = tid; blk < BINB; blk += 256) {
        const int2* src = subbuf + csta[blk];
        int l = clen[blk];
        for (int k = 0; k < l; ++k) {
            int2 rec = src[k];
            int rl = (u32)rec.x >> 18;
            int dst = atomicAdd(&lcur[rl], 1);
            if (dst < CAPB) sbuf[dst] = make_int2(rec.x & 0x3FFFF, rec.y);
        }
    }
    __syncthreads();
    int T = stot; if (T > CAPB) T = CAPB;
    for (int j = tid; j < T; j += 256)       // purely sequential coalesced stores
        cicv[base + j] = sbuf[j];
}

// ---- x0 = concat(embeddings) -> bf16 xa; acc = fp32 copy; echo out fused ----
__global__ void k_init(const float4* __restrict__ ue, const float4* __restrict__ ie,
                       const float4* __restrict__ be, ushort4* __restrict__ xa,
                       float4* __restrict__ acc, float4* __restrict__ out4) {
    int i4 = blockIdx.x * blockDim.x + threadIdx.x;   // unit of 4 floats
    if (i4 >= NN * D / 4) return;
    float4 v;
    if (i4 < NU * D / 4)             v = ue[i4];
    else if (i4 < (NU + NI) * D / 4) v = ie[i4 - NU * D / 4];
    else                             v = be[i4 - (NU + NI) * D / 4];
    acc[i4] = v;
    ushort4 h;
    h.x = f2bf(v.x); h.y = f2bf(v.y); h.z = f2bf(v.z); h.w = f2bf(v.w);
    xa[i4] = h;
    if (i4 < (NU + NI) * D / 4)                       // echo user+item (same order)
        out4[NN * D / 4 + i4] = v;
}

__device__ __forceinline__ void acc8(float f, uint4 h, float* s) {
    union { u32 i; float v; } t;
    t.i = h.x << 16;         s[0] += f * t.v;
    t.i = h.x & 0xffff0000u; s[1] += f * t.v;
    t.i = h.y << 16;         s[2] += f * t.v;
    t.i = h.y & 0xffff0000u; s[3] += f * t.v;
    t.i = h.z << 16;         s[4] += f * t.v;
    t.i = h.z & 0xffff0000u; s[5] += f * t.v;
    t.i = h.w << 16;         s[6] += f * t.v;
    t.i = h.w & 0xffff0000u; s[7] += f * t.v;
}

// ---- SpMM: one wave per row; 8 edges per gather instr, 32 edges/iter ----
template<int LAST>
__global__ __launch_bounds__(256) void k_spmm(
    const int* __restrict__ off, const int* __restrict__ cnt,
    const int2* __restrict__ cicv,
    const u16* __restrict__ xin, uint4* __restrict__ xout,
    float4* __restrict__ acc, float4* __restrict__ out) {
    int gid  = blockIdx.x * blockDim.x + threadIdx.x;
    int row  = gid >> 6;
    int lane = threadIdx.x & 63;
    if (row >= NN) return;
    int base = __builtin_amdgcn_readfirstlane(off[row]);
    int deg  = __builtin_amdgcn_readfirstlane(cnt[row]);
    int q = lane >> 3;
    int p = lane & 7;
    float s[8] = {0.f, 0.f, 0.f, 0.f, 0.f, 0.f, 0.f, 0.f};
    for (int e = 0; e < deg; e += 32) {
        int2 r0 = cicv[base + e + q];           // 8-lane broadcast groups
        int2 r1 = cicv[base + e + 8 + q];
        int2 r2 = cicv[base + e + 16 + q];
        int2 r3 = cicv[base + e + 24 + q];
        bool ok0 = (e + q)      < deg;
        bool ok1 = (e + 8 + q)  < deg;
        bool ok2 = (e + 16 + q) < deg;
        bool ok3 = (e + 24 + q) < deg;
        int c0 = ok0 ? r0.x : 0;  float f0 = ok0 ? __int_as_float(r0.y) : 0.f;
        int c1 = ok1 ? r1.x : 0;  float f1 = ok1 ? __int_as_float(r1.y) : 0.f;
        int c2 = ok2 ? r2.x : 0;  float f2 = ok2 ? __int_as_float(r2.y) : 0.f;
        int c3 = ok3 ? r3.x : 0;  float f3 = ok3 ? __int_as_float(r3.y) : 0.f;
        uint4 h0 = *(const uint4*)(xin + (size_t)c0 * D + p * 8);   // 8 x 128B rows
        uint4 h1 = *(const uint4*)(xin + (size_t)c1 * D + p * 8);
        uint4 h2 = *(const uint4*)(xin + (size_t)c2 * D + p * 8);
        uint4 h3 = *(const uint4*)(xin + (size_t)c3 * D + p * 8);
        acc8(f0, h0, s);
        acc8(f1, h1, s);
        acc8(f2, h2, s);
        acc8(f3, h3, s);
    }
#pragma unroll
    for (int k = 0; k < 8; ++k) {
        s[k] += __shfl_xor(s[k], 8);
        s[k] += __shfl_xor(s[k], 16);
        s[k] += __shfl_xor(s[k], 32);
    }
    int o16 = row * 16 + p * 2;                 // float4 index (2 per lane)
    if (LAST) {
        if (q == 0) {
            float4 a0 = acc[o16], a1 = acc[o16 + 1];
            out[o16]     = make_float4((a0.x + s[0]) * 0.25f, (a0.y + s[1]) * 0.25f,
                                       (a0.z + s[2]) * 0.25f, (a0.w + s[3]) * 0.25f);
            out[o16 + 1] = make_float4((a1.x + s[4]) * 0.25f, (a1.y + s[5]) * 0.25f,
                                       (a1.z + s[6]) * 0.25f, (a1.w + s[7]) * 0.25f);
        }
    } else {
        if (q == 0) {
            float4 a0 = acc[o16], a1 = acc[o16 + 1];
            acc[o16]     = make_float4(a0.x + s[0], a0.y + s[1], a0.z + s[2], a0.w + s[3]);
            acc[o16 + 1] = make_float4(a1.x + s[4], a1.y + s[5], a1.z + s[6], a1.w + s[7]);
        } else if (q == 1) {
            uint4 hh;
            hh.x = (u32)f2bf(s[0]) | ((u32)f2bf(s[1]) << 16);
            hh.y = (u32)f2bf(s[2]) | ((u32)f2bf(s[3]) << 16);
            hh.z = (u32)f2bf(s[4]) | ((u32)f2bf(s[5]) << 16);
            hh.w = (u32)f2bf(s[6]) | ((u32)f2bf(s[7]) << 16);
            xout[row * 8 + p] = hh;
        }
    }
}

extern "C" void kernel_launch(void* const* d_in, const int* in_sizes, int n_in,
                              void* d_out, int out_size, void* d_ws, size_t ws_size,
                              hipStream_t stream) {
    const int*   rows = (const int*)d_in[0];
    const int*   cols = (const int*)d_in[1];
    const float* vals = (const float*)d_in[2];
    float* out = (float*)d_out;

    char* w = (char*)d_ws;
    size_t p = 0;
#define WALLOC(var, type, count) \
    type* var = (type*)(w + p); p += (((size_t)(count) * sizeof(type)) + 255) & ~(size_t)255;
    WALLOC(gtotal,  int, 64)
    WALLOC(off,     int, NN)
    WALLOC(cnt,     int, NN)
    WALLOC(prefarr, int, (size_t)BINB * PSTR)       // 4.85 MB
    // overlay region: subbuf (80 MB) is dead after k_csr; xa/xb/acc (77.3 MB) reuse it
    size_t regA = p;
    int2* subbuf = (int2*)(w + regA);
    size_t subbuf_sz = ((size_t)NE * sizeof(int2) + 255) & ~(size_t)255;
    u16*   xa  = (u16*)(w + regA);
    u16*   xb  = (u16*)(w + regA + (size_t)NN * D * sizeof(u16));
    float* acc = (float*)(w + regA + 2 * (size_t)NN * D * sizeof(u16));
    p = regA + subbuf_sz;
    WALLOC(cicv, int2, (size_t)NE + 32)             // +32 pad: spmm tail (masked)
#undef WALLOC
    (void)p; (void)ws_size; (void)in_sizes; (void)n_in; (void)out_size;

    hipMemsetAsync(gtotal, 0, sizeof(int), stream);

    k_bin<<<BINB, BINT, 0, stream>>>(rows, cols, vals, prefarr, subbuf);
    k_csr<<<NBUCK, 256, 0, stream>>>(prefarr, subbuf, off, cnt, gtotal, cicv);
    k_init<<<(NN * D / 4 + 255) / 256, 256, 0, stream>>>(
        (const float4*)d_in[3], (const float4*)d_in[4],
        (const float4*)d_in[5], (ushort4*)xa, (float4*)acc, (float4*)out);

    int spmm_blocks = NN / 4;   // 4 waves (rows) per 256-thread block; NN%4==0
    k_spmm<0><<<spmm_blocks, 256, 0, stream>>>(off, cnt, cicv, xa, (uint4*)xb,
                                               (float4*)acc, (float4*)out);
    k_spmm<0><<<spmm_blocks, 256, 0, stream>>>(off, cnt, cicv, xb, (uint4*)xa,
                                               (float4*)acc, (float4*)out);
    k_spmm<1><<<spmm_blocks, 256, 0, stream>>>(off, cnt, cicv, xa, (uint4*)xb,
                                               (float4*)acc, (float4*)out);
}

// Round 15
// 935.959 us; speedup vs baseline: 1.1050x; 1.1050x over previous
//
#include <hip/hip_runtime.h>
#include <hip/hip_bf16.h>
#include <stdint.h>

#define NU 100000
#define NI 50000
#define NB 1000
#define NN 151000      // total nodes
#define D  64
#define NE 10000000

#define BSH   6                   // 64 rows per bucket
#define BROWS 64
#define NBUCK 2360                // ceil(NN / 64)
#define CAPB  5632                // k_csr LDS capacity (bucket mean 4238, +21 sigma)
#define BINB  1536                // k_bin blocks; window <= 6511 recs fits 64KB LDS
#define BINT  1024                // k_bin threads per block
#define SBCAP 6512                // >= ceil(NE/BINB) = 6511
#define PSTR  2368                // prefarr row stride (>= NBUCK+1)

typedef unsigned short u16;
typedef unsigned int   u32;

__device__ __forceinline__ u16 f2bf(float f) {
    union { float f; u32 i; } c; c.f = f;
    u32 lsb = (c.i >> 16) & 1;          // round-to-nearest-even bf16
    c.i += 0x7fffu + lsb;
    return (u16)(c.i >> 16);
}

__device__ __forceinline__ void cvt8(uint4 h, float* f) {
    union { u32 i; float v; } t;
    t.i = h.x << 16;         f[0] = t.v;
    t.i = h.x & 0xffff0000u; f[1] = t.v;
    t.i = h.y << 16;         f[2] = t.v;
    t.i = h.y & 0xffff0000u; f[3] = t.v;
    t.i = h.z << 16;         f[4] = t.v;
    t.i = h.z & 0xffff0000u; f[5] = t.v;
    t.i = h.w << 16;         f[6] = t.v;
    t.i = h.w & 0xffff0000u; f[7] = t.v;
}

// ---- phase 1: LDS-resident counting sort of the block's window (61.5KB LDS,
// under the 64KB/workgroup line). Random stores never leave the CU; global
// writes are a perfectly coalesced sequential dump + the prefix row.
__global__ __launch_bounds__(BINT) void k_bin(
    const int* __restrict__ rows, const int* __restrict__ cols,
    const float* __restrict__ vals,
    int* __restrict__ prefarr, int2* __restrict__ subbuf) {
    __shared__ int hc[NBUCK];       // 9.4 KB: histogram, then scatter cursor
    __shared__ int2 sbuf[SBCAP];    // 52.1 KB record staging; head doubles as tsum
    int* tsum = (int*)sbuf;         // scan scratch (dead before records written)
    int b = blockIdx.x, tid = threadIdx.x;
    long e0 = (long)b * NE / BINB;
    long e1 = (long)(b + 1) * NE / BINB;
    for (int j = tid; j < NBUCK; j += BINT) hc[j] = 0;
    __syncthreads();
    for (long i = e0 + tid; i < e1; i += BINT)
        atomicAdd(&hc[rows[i] >> BSH], 1);              // LDS atomic
    __syncthreads();
    // block-level exclusive scan over 2360 bucket counts (3 per thread)
    int base3 = tid * 3;
    int v0 = (base3     < NBUCK) ? hc[base3]     : 0;
    int v1 = (base3 + 1 < NBUCK) ? hc[base3 + 1] : 0;
    int v2 = (base3 + 2 < NBUCK) ? hc[base3 + 2] : 0;
    int lsum = v0 + v1 + v2;
    tsum[tid] = lsum;
    __syncthreads();
    for (int d = 1; d < BINT; d <<= 1) {                // Hillis-Steele inclusive
        int t = (tid >= d) ? tsum[tid - d] : 0;
        __syncthreads();
        tsum[tid] += t;
        __syncthreads();
    }
    int excl = tsum[tid] - lsum;
    int* prow = prefarr + (size_t)b * PSTR;
    if (base3     < NBUCK) { hc[base3]     = excl;           prow[base3]     = excl; }
    if (base3 + 1 < NBUCK) { hc[base3 + 1] = excl + v0;      prow[base3 + 1] = excl + v0; }
    if (base3 + 2 < NBUCK) { hc[base3 + 2] = excl + v0 + v1; prow[base3 + 2] = excl + v0 + v1; }
    if (tid == BINT - 1) prow[NBUCK] = tsum[tid];       // == e1-e0
    __syncthreads();                                    // tsum dead; records begin
    for (long i = e0 + tid; i < e1; i += BINT) {
        int r = rows[i];
        int pos = atomicAdd(&hc[r >> BSH], 1);          // LDS atomic rank
        sbuf[pos] = make_int2(((r & (BROWS - 1)) << 18) | cols[i],
                              __float_as_int(vals[i]));
    }
    __syncthreads();
    int T = (int)(e1 - e0);
    for (int j = tid; j < T; j += BINT)                 // coalesced sequential dump
        subbuf[e0 + j] = sbuf[j];
}

// ---- phase 2: per-bucket CSR build; gather per-window chunks (L3-resident
// reads, no RMW), order in LDS, dump sequentially.
__global__ __launch_bounds__(256) void k_csr(
    const int* __restrict__ prefarr, const int2* __restrict__ subbuf,
    int* __restrict__ off, int* __restrict__ cnt, int* __restrict__ gtotal,
    int2* __restrict__ cicv) {
    __shared__ int rcnt[BROWS], rexc[BROWS], lcur[BROWS];
    __shared__ int csta[BINB], clen[BINB];   // 12.3 KB
    __shared__ int sbase, stot;
    __shared__ int2 sbuf[CAPB];              // 45 KB  (total ~58.2 KB < 64KB)
    int b = blockIdx.x, tid = threadIdx.x;
    for (int blk = tid; blk < BINB; blk += 256) {
        const int* prow = prefarr + (size_t)blk * PSTR;
        int s = prow[b];
        int e = prow[b + 1];
        csta[blk] = (int)((long)blk * NE / BINB) + s;
        clen[blk] = e - s;
    }
    if (tid < BROWS) rcnt[tid] = 0;
    __syncthreads();
    // pass 1: row histogram from chunk reads
    for (int blk = tid; blk < BINB; blk += 256) {
        const int2* src = subbuf + csta[blk];
        int l = clen[blk];
        for (int k = 0; k < l; ++k)
            atomicAdd(&rcnt[(u32)src[k].x >> 18], 1);
    }
    __syncthreads();
    if (tid < 64) {
        int v = rcnt[tid], x = v;
        for (int d = 1; d < 64; d <<= 1) {
            int t = __shfl_up(x, d);
            if (tid >= d) x += t;
        }
        rexc[tid] = x - v;
        if (tid == 63) {
            stot = x;
            sbase = atomicAdd(gtotal, x);   // disjoint segments, order-free
        }
    }
    __syncthreads();
    int base = sbase;
    if (tid < BROWS) {
        int r = b * BROWS + tid;
        if (r < NN) { off[r] = base + rexc[tid]; cnt[r] = rcnt[tid]; }
        lcur[tid] = rexc[tid];
    }
    __syncthreads();
    // pass 2: re-read chunks, scatter into LDS in CSR order
    for (int blk = tid; blk < BINB; blk += 256) {
        const int2* src = subbuf + csta[blk];
        int l = clen[blk];
        for (int k = 0; k < l; ++k) {
            int2 rec = src[k];
            int rl = (u32)rec.x >> 18;
            int dst = atomicAdd(&lcur[rl], 1);
            if (dst < CAPB) sbuf[dst] = make_int2(rec.x & 0x3FFFF, rec.y);
        }
    }
    __syncthreads();
    int T = stot; if (T > CAPB) T = CAPB;
    for (int j = tid; j < T; j += 256)       // purely sequential coalesced stores
        cicv[base + j] = sbuf[j];
}

// ---- x0 = concat(embeddings) -> bf16; echo user/item to out. NO acc buffer. ----
__global__ void k_init(const float4* __restrict__ ue, const float4* __restrict__ ie,
                       const float4* __restrict__ be, ushort4* __restrict__ x0,
                       float4* __restrict__ out4) {
    int i4 = blockIdx.x * blockDim.x + threadIdx.x;   // unit of 4 floats
    if (i4 >= NN * D / 4) return;
    float4 v;
    if (i4 < NU * D / 4)             v = ue[i4];
    else if (i4 < (NU + NI) * D / 4) v = ie[i4 - NU * D / 4];
    else                             v = be[i4 - (NU + NI) * D / 4];
    ushort4 h;
    h.x = f2bf(v.x); h.y = f2bf(v.y); h.z = f2bf(v.z); h.w = f2bf(v.w);
    x0[i4] = h;
    if (i4 < (NU + NI) * D / 4)                       // echo user+item (same order)
        out4[NN * D / 4 + i4] = v;
}

__device__ __forceinline__ void acc8(float f, uint4 h, float* s) {
    float x[8];
    cvt8(h, x);
#pragma unroll
    for (int k = 0; k < 8; ++k) s[k] += f * x[k];
}

// ---- SpMM: one wave per row; 8 gathers in flight (64 edges/iter).
// lane = (q,p): q=lane>>3 edge slot 0..7, p=lane&7 dim octet (16B/lane loads).
// Non-LAST: write bf16 y to xout. LAST: out = (x0+y1+y2+y3)/4 (reads b0,b1,xin).
template<int LAST>
__global__ __launch_bounds__(256) void k_spmm(
    const int* __restrict__ off, const int* __restrict__ cnt,
    const int2* __restrict__ cicv,
    const u16* __restrict__ xin, uint4* __restrict__ xout,
    const u16* __restrict__ b0, const u16* __restrict__ b1,
    float4* __restrict__ out) {
    int gid  = blockIdx.x * blockDim.x + threadIdx.x;
    int row  = gid >> 6;
    int lane = threadIdx.x & 63;
    if (row >= NN) return;
    int base = __builtin_amdgcn_readfirstlane(off[row]);
    int deg  = __builtin_amdgcn_readfirstlane(cnt[row]);
    int q = lane >> 3;
    int p = lane & 7;
    float s[8] = {0.f, 0.f, 0.f, 0.f, 0.f, 0.f, 0.f, 0.f};
    for (int e = 0; e < deg; e += 64) {
        int2 rr[8];
#pragma unroll
        for (int k = 0; k < 8; ++k)
            rr[k] = cicv[base + e + 8 * k + q];   // 8-lane broadcast groups
        int   c[8];
        float f[8];
#pragma unroll
        for (int k = 0; k < 8; ++k) {
            bool ok = (e + 8 * k + q) < deg;
            c[k] = ok ? rr[k].x : 0;
            f[k] = ok ? __int_as_float(rr[k].y) : 0.f;
        }
        uint4 h[8];
#pragma unroll
        for (int k = 0; k < 8; ++k)
            h[k] = *(const uint4*)(xin + (size_t)c[k] * D + p * 8);  // 8x128B rows
#pragma unroll
        for (int k = 0; k < 8; ++k)
            acc8(f[k], h[k], s);
    }
#pragma unroll
    for (int k = 0; k < 8; ++k) {
        s[k] += __shfl_xor(s[k], 8);
        s[k] += __shfl_xor(s[k], 16);
        s[k] += __shfl_xor(s[k], 32);
    }
    if (LAST) {
        if (q == 0) {
            uint4 h0 = *(const uint4*)(b0  + (size_t)row * D + p * 8);
            uint4 h1 = *(const uint4*)(b1  + (size_t)row * D + p * 8);
            uint4 h2 = *(const uint4*)(xin + (size_t)row * D + p * 8);
            float f0[8], f1[8], f2[8];
            cvt8(h0, f0); cvt8(h1, f1); cvt8(h2, f2);
            int o16 = row * 16 + p * 2;
            out[o16]     = make_float4((f0[0]+f1[0]+f2[0]+s[0])*0.25f,
                                       (f0[1]+f1[1]+f2[1]+s[1])*0.25f,
                                       (f0[2]+f1[2]+f2[2]+s[2])*0.25f,
                                       (f0[3]+f1[3]+f2[3]+s[3])*0.25f);
            out[o16 + 1] = make_float4((f0[4]+f1[4]+f2[4]+s[4])*0.25f,
                                       (f0[5]+f1[5]+f2[5]+s[5])*0.25f,
                                       (f0[6]+f1[6]+f2[6]+s[6])*0.25f,
                                       (f0[7]+f1[7]+f2[7]+s[7])*0.25f);
        }
    } else {
        if (q == 0) {
            uint4 hh;
            hh.x = (u32)f2bf(s[0]) | ((u32)f2bf(s[1]) << 16);
            hh.y = (u32)f2bf(s[2]) | ((u32)f2bf(s[3]) << 16);
            hh.z = (u32)f2bf(s[4]) | ((u32)f2bf(s[5]) << 16);
            hh.w = (u32)f2bf(s[6]) | ((u32)f2bf(s[7]) << 16);
            xout[row * 8 + p] = hh;
        }
    }
}

extern "C" void kernel_launch(void* const* d_in, const int* in_sizes, int n_in,
                              void* d_out, int out_size, void* d_ws, size_t ws_size,
                              hipStream_t stream) {
    const int*   rows = (const int*)d_in[0];
    const int*   cols = (const int*)d_in[1];
    const float* vals = (const float*)d_in[2];
    float* out = (float*)d_out;

    char* w = (char*)d_ws;
    size_t p = 0;
#define WALLOC(var, type, count) \
    type* var = (type*)(w + p); p += (((size_t)(count) * sizeof(type)) + 255) & ~(size_t)255;
    WALLOC(gtotal,  int, 64)
    WALLOC(off,     int, NN)
    WALLOC(cnt,     int, NN)
    WALLOC(prefarr, int, (size_t)BINB * PSTR)       // 14.6 MB
    // overlay region: subbuf (80 MB) dead after k_csr; x0/y1/y2 (58 MB) reuse it
    size_t regA = p;
    int2* subbuf = (int2*)(w + regA);
    size_t subbuf_sz = ((size_t)NE * sizeof(int2) + 255) & ~(size_t)255;
    u16* x0 = (u16*)(w + regA);
    u16* y1 = (u16*)(w + regA + (size_t)NN * D * sizeof(u16));
    u16* y2 = (u16*)(w + regA + 2 * (size_t)NN * D * sizeof(u16));
    p = regA + subbuf_sz;
    WALLOC(cicv, int2, (size_t)NE + 64)             // +64 pad: spmm tail (masked)
#undef WALLOC
    (void)p; (void)ws_size; (void)in_sizes; (void)n_in; (void)out_size;

    hipMemsetAsync(gtotal, 0, sizeof(int), stream);

    k_bin<<<BINB, BINT, 0, stream>>>(rows, cols, vals, prefarr, subbuf);
    k_csr<<<NBUCK, 256, 0, stream>>>(prefarr, subbuf, off, cnt, gtotal, cicv);
    k_init<<<(NN * D / 4 + 255) / 256, 256, 0, stream>>>(
        (const float4*)d_in[3], (const float4*)d_in[4],
        (const float4*)d_in[5], (ushort4*)x0, (float4*)out);

    int spmm_blocks = NN / 4;   // 4 waves (rows) per 256-thread block; NN%4==0
    // layer 1: x0 -> y1
    k_spmm<0><<<spmm_blocks, 256, 0, stream>>>(off, cnt, cicv, x0, (uint4*)y1,
                                               x0, x0, (float4*)out);
    // layer 2: y1 -> y2
    k_spmm<0><<<spmm_blocks, 256, 0, stream>>>(off, cnt, cicv, y1, (uint4*)y2,
                                               x0, x0, (float4*)out);
    // layer 3: y2 -> out = (x0+y1+y2+y3)/4
    k_spmm<1><<<spmm_blocks, 256, 0, stream>>>(off, cnt, cicv, y2, (uint4*)y1,
                                               x0, y1, (float4*)out);
}